// Round 5
// baseline (799.673 us; speedup 1.0000x reference)
//
#include <hip/hip_runtime.h>

typedef __attribute__((ext_vector_type(8))) short short8;
typedef __attribute__((ext_vector_type(4))) float float4v;
typedef __attribute__((ext_vector_type(4))) unsigned int uint4v;
typedef __attribute__((ext_vector_type(4))) unsigned short ushort4v;

__device__ __forceinline__ float lrelu(float v) { return v >= 0.f ? v : 0.01f * v; }

__device__ __forceinline__ unsigned short f2bf(float x) {
    union { float f; unsigned u; } c; c.f = x;
    unsigned r = (c.u + 0x7FFFu + ((c.u >> 16) & 1u)) >> 16;
    return (unsigned short)r;
}
__device__ __forceinline__ float bf2f(unsigned short h) {
    union { unsigned u; float f; } c; c.u = ((unsigned)h) << 16;
    return c.f;
}

// async global->LDS, 16B per lane. LDS dest must be wave-uniform base
// (HW adds lane*16); global src is per-lane (pre-swizzled).
__device__ __forceinline__ void gload16(const unsigned short* g, unsigned short* l) {
    __builtin_amdgcn_global_load_lds(
        (const __attribute__((address_space(1))) unsigned int*)g,
        (__attribute__((address_space(3))) unsigned int*)l, 16, 0, 0);
}

// ===========================================================================
// Shared MFMA core: C[128x128] += A[128xK] * B[128xK]^T, K=512, split-bf16
// (hi*hi + hi*lo + lo*hi -> ~fp32 precision). 256 threads, 4 waves 2x2.
// LDS: 4 tiles [128][64] bf16. global_load_lds direct staging: LDS linear,
// global source pre-swizzled with the same XOR involution the reads use.
// ===========================================================================
__device__ __forceinline__ void mfma_core(
    const unsigned short* __restrict__ Ah, const unsigned short* __restrict__ Al, int lda,
    const unsigned short* __restrict__ Bh, const unsigned short* __restrict__ Bl, int ldb,
    unsigned short* lds, float4v acc[4][4]) {
    const int tid = threadIdx.x;
    const int lane = tid & 63, wave = tid >> 6;
    const int wm = wave >> 1, wn = wave & 1;
    const int l15 = lane & 15, lhi = lane >> 4;
    unsigned short* LAh = lds;
    unsigned short* LAl = lds + 8192;
    unsigned short* LBh = lds + 16384;
    unsigned short* LBl = lds + 24576;

    for (int k0 = 0; k0 < 512; k0 += 64) {
#pragma unroll
        for (int tile = 0; tile < 4; ++tile) {
            const unsigned short* s = (tile == 0) ? Ah : (tile == 1) ? Al : (tile == 2) ? Bh : Bl;
            int ld = (tile < 2) ? lda : ldb;
            unsigned short* dbase = lds + tile * 8192;
#pragma unroll
            for (int it = 0; it < 4; ++it) {
                int idx = it * 256 + tid;
                int row = idx >> 3, ch = idx & 7;
                // linear LDS dest (wave-uniform base), swizzled global src
                gload16(&s[row * ld + k0 + ((ch ^ (row & 7)) << 3)],
                        dbase + ((it * 256 + wave * 64) << 3));
            }
        }
        __syncthreads();
#pragma unroll
        for (int ks = 0; ks < 2; ++ks) {
            short8 ah[4], al[4], bh[4], bl[4];
#pragma unroll
            for (int m = 0; m < 4; ++m) {
                int r = wm * 64 + m * 16 + l15;
                int off = r * 64 + (((ks * 4 + lhi) ^ (r & 7)) * 8);
                ah[m] = *(const short8*)&LAh[off];
                al[m] = *(const short8*)&LAl[off];
            }
#pragma unroll
            for (int n = 0; n < 4; ++n) {
                int r = wn * 64 + n * 16 + l15;
                int off = r * 64 + (((ks * 4 + lhi) ^ (r & 7)) * 8);
                bh[n] = *(const short8*)&LBh[off];
                bl[n] = *(const short8*)&LBl[off];
            }
#pragma unroll
            for (int m = 0; m < 4; ++m)
#pragma unroll
                for (int n = 0; n < 4; ++n) {
                    acc[m][n] = __builtin_amdgcn_mfma_f32_16x16x32_bf16(ah[m], bh[n], acc[m][n], 0, 0, 0);
                    acc[m][n] = __builtin_amdgcn_mfma_f32_16x16x32_bf16(ah[m], bl[n], acc[m][n], 0, 0, 0);
                    acc[m][n] = __builtin_amdgcn_mfma_f32_16x16x32_bf16(al[m], bh[n], acc[m][n], 0, 0, 0);
                }
        }
        __syncthreads();
    }
}

// ---------------------------------------------------------------------------
// Wg_w = W_w @ g_w  (fp32, small: 0.27 GFLOP)
// ---------------------------------------------------------------------------
#define TS 64
#define KS 16
__global__ __launch_bounds__(256) void k_gemm_nn(const float* __restrict__ A,
                                                 const float* __restrict__ B,
                                                 float* __restrict__ C,
                                                 int M, int N, int K) {
    __shared__ float As[TS][KS + 1];
    __shared__ float Bs[KS][TS];
    int tid = threadIdx.x;
    int tx = tid & 15, ty = tid >> 4;
    int i0 = blockIdx.y * TS, j0 = blockIdx.x * TS;
    float acc[4][4] = {};
    for (int k0 = 0; k0 < K; k0 += KS) {
        {
            int c = tid & 15, r0 = tid >> 4;
#pragma unroll
            for (int l = 0; l < 4; ++l) As[r0 + l * 16][c] = A[(i0 + r0 + l * 16) * K + k0 + c];
        }
        {
            int j = tid & 63, r0 = tid >> 6;
#pragma unroll
            for (int l = 0; l < 4; ++l) Bs[r0 + l * 4][j] = B[(k0 + r0 + l * 4) * N + j0 + j];
        }
        __syncthreads();
#pragma unroll
        for (int kk = 0; kk < KS; ++kk) {
            float4 b4 = *(const float4*)&Bs[kk][tx * 4];
#pragma unroll
            for (int i = 0; i < 4; ++i) {
                float a = As[ty * 4 + i][kk];
                acc[i][0] += a * b4.x; acc[i][1] += a * b4.y;
                acc[i][2] += a * b4.z; acc[i][3] += a * b4.w;
            }
        }
        __syncthreads();
    }
#pragma unroll
    for (int i = 0; i < 4; ++i) {
        float4 v = {acc[i][0], acc[i][1], acc[i][2], acc[i][3]};
        *(float4*)&C[(i0 + ty * 4 + i) * N + j0 + tx * 4] = v;
    }
}

// ---------------------------------------------------------------------------
// Split fp32 weight matrices into bf16 hi/lo. grid (256, 5), block 256.
// ---------------------------------------------------------------------------
__global__ __launch_bounds__(256) void k_split_w(
    const float* __restrict__ tw, const float* __restrict__ fw,
    const float* __restrict__ wgw, const float* __restrict__ p1w,
    const float* __restrict__ p2w, unsigned short* __restrict__ Whi,
    unsigned short* __restrict__ Wlo, unsigned short* __restrict__ p1h,
    unsigned short* __restrict__ p1l, unsigned short* __restrict__ p2h,
    unsigned short* __restrict__ p2l) {
    int z = blockIdx.y;
    const float* src = (z == 0) ? tw : (z == 1) ? fw : (z == 2) ? wgw : (z == 3) ? p1w : p2w;
    unsigned short* dh = (z < 3) ? Whi + z * 262144 : ((z == 3) ? p1h : p2h);
    unsigned short* dl = (z < 3) ? Wlo + z * 262144 : ((z == 3) ? p1l : p2l);
    int i4 = blockIdx.x * 256 + threadIdx.x;
    float4v v = ((const float4v*)src)[i4];
    ushort4v h, l;
#pragma unroll
    for (int j = 0; j < 4; ++j) {
        h[j] = f2bf(v[j]);
        l[j] = f2bf(v[j] - bf2f(h[j]));
    }
    ((ushort4v*)dh)[i4] = h;
    ((ushort4v*)dl)[i4] = l;
}

// ---------------------------------------------------------------------------
// Transpose+split inputs: Xt[((b*128+t)*3+k)*512 + c] = in_k[b][c][t] (hi/lo)
// ---------------------------------------------------------------------------
__global__ __launch_bounds__(256) void k_splitx(const float* __restrict__ o1,
                                                const float* __restrict__ o2,
                                                const float* __restrict__ o3,
                                                unsigned short* __restrict__ Xh,
                                                unsigned short* __restrict__ Xl) {
    int z = blockIdx.z;
    int b = z / 3, k = z - b * 3;
    const float* In = (k == 0) ? o1 : ((k == 1) ? o2 : o3);
    int c0 = blockIdx.x * 32, t0 = blockIdx.y * 32;
    __shared__ float tile[32][33];
    int tx = threadIdx.x, ty = threadIdx.y;
#pragma unroll
    for (int i = 0; i < 4; ++i)
        tile[ty + i * 8][tx] = In[(b * 512 + c0 + ty + i * 8) * 128 + t0 + tx];
    __syncthreads();
#pragma unroll
    for (int i = 0; i < 4; ++i) {
        int t = t0 + ty + i * 8;
        float v = tile[tx][ty + i * 8];
        unsigned short h = f2bf(v), l = f2bf(v - bf2f(h));
        int idx = ((b * 128 + t) * 3 + k) * 512 + c0 + tx;
        Xh[idx] = h;
        Xl[idx] = l;
    }
}

// ---------------------------------------------------------------------------
// Stage A via MFMA: grid (48, 12): x = b*3+kin, y = o-tile (wsel = y>>2)
// ---------------------------------------------------------------------------
__global__ __launch_bounds__(256) void k_ga(
    const unsigned short* __restrict__ Whi, const unsigned short* __restrict__ Wlo,
    const unsigned short* __restrict__ Xh, const unsigned short* __restrict__ Xl,
    unsigned short* __restrict__ Thh, unsigned short* __restrict__ Thl,
    unsigned short* __restrict__ Phh, unsigned short* __restrict__ Phl,
    float* __restrict__ Wg) {
    __shared__ unsigned short lds[32768];
    int bk = blockIdx.x, y = blockIdx.y;
    int b = bk / 3, kin = bk - b * 3;
    int bbase = (b * 384 + kin) * 512;
    float4v acc[4][4];
#pragma unroll
    for (int m = 0; m < 4; ++m)
#pragma unroll
        for (int n = 0; n < 4; ++n) acc[m][n] = (float4v){0.f, 0.f, 0.f, 0.f};

    mfma_core(Whi + y * 128 * 512, Wlo + y * 128 * 512, 512,
              Xh + bbase, Xl + bbase, 1536, lds, acc);

    int lane = threadIdx.x & 63, wave = threadIdx.x >> 6;
    int wm = wave >> 1, wn = wave & 1, l15 = lane & 15, lhi = lane >> 4;
    int wsel = y >> 2, o0 = (y & 3) * 128;
#pragma unroll
    for (int m = 0; m < 4; ++m)
#pragma unroll
        for (int n = 0; n < 4; ++n) {
            int o_in = wm * 64 + m * 16 + lhi * 4;
            int t = wn * 64 + n * 16 + l15;
            int idx = bbase + t * 1536 + o0 + o_in;
            if (wsel == 2) {
                *(float4v*)&Wg[idx] = acc[m][n];
            } else {
                ushort4v h, l;
#pragma unroll
                for (int i = 0; i < 4; ++i) {
                    float v = acc[m][n][i];
                    h[i] = f2bf(v);
                    l[i] = f2bf(v - bf2f(h[i]));
                }
                unsigned short* dh = wsel ? Phh : Thh;
                unsigned short* dl = wsel ? Phl : Thl;
                *(ushort4v*)&dh[idx] = h;
                *(ushort4v*)&dl[idx] = l;
            }
        }
}

// ---------------------------------------------------------------------------
// Gram via MFMA. grid 144, XCD-swizzled so same-b mats share an XCD's L2.
// ---------------------------------------------------------------------------
__global__ __launch_bounds__(256) void k_gram2(
    const unsigned short* __restrict__ Thh, const unsigned short* __restrict__ Thl,
    const unsigned short* __restrict__ Phh, const unsigned short* __restrict__ Phl,
    float* __restrict__ D) {
    __shared__ unsigned short lds[32768];
    int orig = blockIdx.x;
    int mat = (orig & 7) * 18 + (orig >> 3);  // 144 = 8 * 18, bijective
    int b = mat / 9, r9 = mat - b * 9, k = r9 / 3, kp = r9 - k * 3;
    int Ab = (b * 384 + k) * 512, Bb = (b * 384 + kp) * 512;
    float4v acc[4][4];
#pragma unroll
    for (int m = 0; m < 4; ++m)
#pragma unroll
        for (int n = 0; n < 4; ++n) acc[m][n] = (float4v){0.f, 0.f, 0.f, 0.f};

    mfma_core(Thh + Ab, Thl + Ab, 1536, Phh + Bb, Phl + Bb, 1536, lds, acc);

    int lane = threadIdx.x & 63, wave = threadIdx.x >> 6;
    int wm = wave >> 1, wn = wave & 1, l15 = lane & 15, lhi = lane >> 4;
    float* Dm = D + mat * 16384;
#pragma unroll
    for (int m = 0; m < 4; ++m)
#pragma unroll
        for (int n = 0; n < 4; ++n) {
            int t2 = wn * 64 + n * 16 + l15;
#pragma unroll
            for (int i = 0; i < 4; ++i) {
                int t1 = wm * 64 + m * 16 + lhi * 4 + i;
                Dm[t1 * 128 + t2] = acc[m][n][i];
            }
        }
}

// ---------------------------------------------------------------------------
// MLP layer via MFMA: C[r][o] = lrelu( A[r,:] . W[o,:] )
// ---------------------------------------------------------------------------
template <bool SPLIT_OUT>
__global__ __launch_bounds__(256) void k_mlp(
    const unsigned short* __restrict__ Ahi, const unsigned short* __restrict__ Alo,
    const unsigned short* __restrict__ Bhi, const unsigned short* __restrict__ Blo,
    unsigned short* __restrict__ Ch, unsigned short* __restrict__ Cl,
    float* __restrict__ Cf) {
    __shared__ unsigned short lds[32768];
    int r0 = blockIdx.x * 128, o0 = blockIdx.y * 128;
    float4v acc[4][4];
#pragma unroll
    for (int m = 0; m < 4; ++m)
#pragma unroll
        for (int n = 0; n < 4; ++n) acc[m][n] = (float4v){0.f, 0.f, 0.f, 0.f};

    mfma_core(Ahi + r0 * 512, Alo + r0 * 512, 512, Bhi + o0 * 512, Blo + o0 * 512, 512, lds, acc);

    int lane = threadIdx.x & 63, wave = threadIdx.x >> 6;
    int wm = wave >> 1, wn = wave & 1, l15 = lane & 15, lhi = lane >> 4;
#pragma unroll
    for (int m = 0; m < 4; ++m)
#pragma unroll
        for (int n = 0; n < 4; ++n) {
            int o = o0 + wn * 64 + n * 16 + l15;
#pragma unroll
            for (int i = 0; i < 4; ++i) {
                int r = r0 + wm * 64 + m * 16 + lhi * 4 + i;
                float v = lrelu(acc[m][n][i]);
                if (SPLIT_OUT) {
                    unsigned short h = f2bf(v), l = f2bf(v - bf2f(h));
                    Ch[r * 512 + o] = h;
                    Cl[r * 512 + o] = l;
                } else {
                    Cf[r * 512 + o] = v;
                }
            }
        }
}

// ---------------------------------------------------------------------------
// Mix: per (b,t): gather f from D, softmax rows (write transposed PmT[m][n]),
// then y[n] accumulators in regs: one Wg load per m, broadcast PmT reads.
// grid 2048 XCD-swizzled (same-b blocks share an XCD's L2), block 512.
// ---------------------------------------------------------------------------
__global__ __launch_bounds__(512) void k_mix(
    const unsigned short* __restrict__ Xh, const unsigned short* __restrict__ Xl,
    const float* __restrict__ Wg, const float* __restrict__ D,
    const float* __restrict__ W_b, unsigned short* __restrict__ Plh,
    unsigned short* __restrict__ Pll) {
    int orig = blockIdx.x;
    int bid = ((orig & 7) << 8) | (orig >> 3);  // 2048 = 8 * 256, bijective
    int b = bid >> 7, t = bid & 127;
    int tid = threadIdx.x;

    __shared__ float Pm[24][28];
    __shared__ float PmT[24][28];  // [m][n]

    for (int idx = tid; idx < 576; idx += 512) {
        int n = idx / 24, m = idx - n * 24;
        int j = n / 3, k = n - j * 3;
        int jp = m / 3, kp = m - jp * 3;
        int t1 = t - 7 + j, t2 = t - 7 + jp;
        float v = 0.f;
        if (t1 >= 0 && t2 >= 0)
            v = D[((((b * 3 + k) * 3 + kp) * 128 + t1) << 7) + t2];
        Pm[n][m] = v;
    }
    __syncthreads();

    if (tid < 24) {
        float mx = -1e30f;
#pragma unroll
        for (int m = 0; m < 24; ++m) mx = fmaxf(mx, Pm[tid][m]);
        float e[24], sum = 0.f;
#pragma unroll
        for (int m = 0; m < 24; ++m) { e[m] = __expf(Pm[tid][m] - mx); sum += e[m]; }
        float inv = 1.0f / sum;
#pragma unroll
        for (int m = 0; m < 24; ++m) PmT[m][tid] = e[m] * inv;
    }
    __syncthreads();

    int o = tid;
    float y[24];
#pragma unroll
    for (int n = 0; n < 24; ++n) y[n] = 0.f;
#pragma unroll
    for (int m = 0; m < 24; ++m) {
        int j = m / 3, k = m - j * 3;
        int tp = t - 7 + j;
        float wgm = (tp >= 0) ? Wg[(((b * 128 + tp) * 3 + k) << 9) + o] : 0.f;
#pragma unroll
        for (int nq = 0; nq < 6; ++nq) {
            float4 p = *(const float4*)&PmT[m][nq * 4];  // wave-uniform: broadcast
            y[nq * 4 + 0] += p.x * wgm;
            y[nq * 4 + 1] += p.y * wgm;
            y[nq * 4 + 2] += p.z * wgm;
            y[nq * 4 + 3] += p.w * wgm;
        }
    }
    float wb = W_b[o];
    float pooled = -1e30f;
#pragma unroll
    for (int n = 0; n < 24; ++n) {
        int j = n / 3, k = n - j * 3;
        int tp = t - 7 + j;
        float xwn = 0.f;
        if (tp >= 0) {
            int base = (((b * 128 + tp) * 3 + k) << 9) + o;
            xwn = bf2f(Xh[base]) + bf2f(Xl[base]);
        }
        pooled = fmaxf(pooled, y[n] + wb + xwn);
    }
    int oidx = ((t * 16 + b) << 9) + o;
    unsigned short h = f2bf(pooled), l = f2bf(pooled - bf2f(h));
    Plh[oidx] = h;
    Pll[oidx] = l;
}

// ---------------------------------------------------------------------------
// out[r] = lrelu( sum_c H[r][c]*p3w[c] + p3b )   one wave per row
// ---------------------------------------------------------------------------
__global__ __launch_bounds__(256) void k_final(const float* __restrict__ H,
                                               const float* __restrict__ p3w,
                                               const float* __restrict__ p3b,
                                               float* __restrict__ out) {
    int r = blockIdx.x * 4 + (threadIdx.x >> 6);
    int lane = threadIdx.x & 63;
    const float4* h4 = (const float4*)&H[r << 9];
    const float4* w4 = (const float4*)p3w;
    float4 a1 = h4[lane], a2 = h4[lane + 64];
    float4 b1 = w4[lane], b2 = w4[lane + 64];
    float s = a1.x * b1.x + a1.y * b1.y + a1.z * b1.z + a1.w * b1.w +
              a2.x * b2.x + a2.y * b2.y + a2.z * b2.z + a2.w * b2.w;
#pragma unroll
    for (int off = 32; off; off >>= 1) s += __shfl_down(s, off, 64);
    if (lane == 0) out[r] = lrelu(s + p3b[0]);
}

extern "C" void kernel_launch(void* const* d_in, const int* in_sizes, int n_in,
                              void* d_out, int out_size, void* d_ws, size_t ws_size,
                              hipStream_t stream) {
    const float* out1 = (const float*)d_in[0];
    const float* out2 = (const float*)d_in[1];
    const float* out3 = (const float*)d_in[2];
    const float* theta_w = (const float*)d_in[3];
    const float* phi_w = (const float*)d_in[4];
    const float* g_w = (const float*)d_in[5];
    const float* W_w = (const float*)d_in[6];
    const float* W_b = (const float*)d_in[7];
    const float* p1_w = (const float*)d_in[8];
    const float* p2_w = (const float*)d_in[9];
    const float* p3_w = (const float*)d_in[10];
    const float* p3_b = (const float*)d_in[11];
    float* outp = (float*)d_out;

    // ---- workspace layout (bytes) ----
    char* wsb = (char*)d_ws;
    float* Wg_w = (float*)(wsb + 0);
    unsigned short* Whi = (unsigned short*)(wsb + 1048576);
    unsigned short* Wlo = (unsigned short*)(wsb + 2621440);
    unsigned short* p1h = (unsigned short*)(wsb + 4194304);
    unsigned short* p1l = (unsigned short*)(wsb + 4718592);
    unsigned short* p2h = (unsigned short*)(wsb + 5242880);
    unsigned short* p2l = (unsigned short*)(wsb + 5767168);
    unsigned short* Xh  = (unsigned short*)(wsb + 6291456);
    unsigned short* Xl  = (unsigned short*)(wsb + 12582912);
    unsigned short* Thh = (unsigned short*)(wsb + 18874368);
    unsigned short* Thl = (unsigned short*)(wsb + 25165824);
    unsigned short* Phh = (unsigned short*)(wsb + 31457280);
    unsigned short* Phl = (unsigned short*)(wsb + 37748736);
    float* Wg = (float*)(wsb + 44040192);
    float* D  = (float*)(wsb + 56623104);
    // aliases (dead-buffer reuse):
    unsigned short* Plh = (unsigned short*)(wsb + 31457280);  // over Phh
    unsigned short* Pll = (unsigned short*)(wsb + 33554432);
    unsigned short* h1h = (unsigned short*)(wsb + 18874368);  // over Thh
    unsigned short* h1l = (unsigned short*)(wsb + 20971520);
    float* h2 = (float*)(wsb + 23068672);

    k_gemm_nn<<<dim3(8, 8), 256, 0, stream>>>(W_w, g_w, Wg_w, 512, 512, 512);
    k_split_w<<<dim3(256, 5), 256, 0, stream>>>(theta_w, phi_w, Wg_w, p1_w, p2_w,
                                                Whi, Wlo, p1h, p1l, p2h, p2l);
    k_splitx<<<dim3(16, 4, 48), dim3(32, 8), 0, stream>>>(out1, out2, out3, Xh, Xl);
    k_ga<<<dim3(48, 12), 256, 0, stream>>>(Whi, Wlo, Xh, Xl, Thh, Thl, Phh, Phl, Wg);
    k_gram2<<<dim3(144), 256, 0, stream>>>(Thh, Thl, Phh, Phl, D);
    k_mix<<<dim3(2048), 512, 0, stream>>>(Xh, Xl, Wg, D, W_b, Plh, Pll);
    k_mlp<true><<<dim3(16, 4), 256, 0, stream>>>(Plh, Pll, p1h, p1l, h1h, h1l, nullptr);
    k_mlp<false><<<dim3(16, 4), 256, 0, stream>>>(h1h, h1l, p2h, p2l, nullptr, nullptr, h2);
    k_final<<<dim3(512), 256, 0, stream>>>(h2, p3_w, p3_b, outp);
}

// Round 6
// 199.505 us; speedup vs baseline: 4.0083x; 4.0083x over previous
//
#include <hip/hip_runtime.h>

typedef __attribute__((ext_vector_type(8))) short short8;
typedef __attribute__((ext_vector_type(4))) float float4v;
typedef __attribute__((ext_vector_type(4))) unsigned int uint4v;
typedef __attribute__((ext_vector_type(4))) unsigned short ushort4v;

__device__ __forceinline__ float lrelu(float v) { return v >= 0.f ? v : 0.01f * v; }

__device__ __forceinline__ unsigned short f2bf(float x) {
    union { float f; unsigned u; } c; c.f = x;
    unsigned r = (c.u + 0x7FFFu + ((c.u >> 16) & 1u)) >> 16;
    return (unsigned short)r;
}
__device__ __forceinline__ float bf2f(unsigned short h) {
    union { unsigned u; float f; } c; c.u = ((unsigned)h) << 16;
    return c.f;
}

// async global->LDS, 16B per lane. LDS dest must be wave-uniform base
// (HW adds lane*16); global src is per-lane (pre-swizzled).
__device__ __forceinline__ void gload16(const unsigned short* g, unsigned short* l) {
    __builtin_amdgcn_global_load_lds(
        (const __attribute__((address_space(1))) unsigned int*)g,
        (__attribute__((address_space(3))) unsigned int*)l, 16, 0, 0);
}

// ===========================================================================
// Shared MFMA core: C[128x128] += A[128xK] * B[128xK]^T, K=512, split-bf16
// (hi*hi + hi*lo + lo*hi -> ~fp32 precision). 256 threads, 4 waves 2x2.
// LDS: 4 tiles [128][64] bf16. global_load_lds direct staging: LDS linear,
// global source pre-swizzled with the same XOR involution the reads use.
// ===========================================================================
__device__ __forceinline__ void mfma_core(
    const unsigned short* __restrict__ Ah, const unsigned short* __restrict__ Al, int lda,
    const unsigned short* __restrict__ Bh, const unsigned short* __restrict__ Bl, int ldb,
    unsigned short* lds, float4v acc[4][4]) {
    const int tid = threadIdx.x;
    const int lane = tid & 63, wave = tid >> 6;
    const int wm = wave >> 1, wn = wave & 1;
    const int l15 = lane & 15, lhi = lane >> 4;
    unsigned short* LAh = lds;
    unsigned short* LAl = lds + 8192;
    unsigned short* LBh = lds + 16384;
    unsigned short* LBl = lds + 24576;

    for (int k0 = 0; k0 < 512; k0 += 64) {
#pragma unroll
        for (int tile = 0; tile < 4; ++tile) {
            const unsigned short* s = (tile == 0) ? Ah : (tile == 1) ? Al : (tile == 2) ? Bh : Bl;
            int ld = (tile < 2) ? lda : ldb;
            unsigned short* dbase = lds + tile * 8192;
#pragma unroll
            for (int it = 0; it < 4; ++it) {
                int idx = it * 256 + tid;
                int row = idx >> 3, ch = idx & 7;
                // linear LDS dest (wave-uniform base), swizzled global src
                gload16(&s[row * ld + k0 + ((ch ^ (row & 7)) << 3)],
                        dbase + ((it * 256 + wave * 64) << 3));
            }
        }
        __syncthreads();
#pragma unroll
        for (int ks = 0; ks < 2; ++ks) {
            short8 ah[4], al[4], bh[4], bl[4];
#pragma unroll
            for (int m = 0; m < 4; ++m) {
                int r = wm * 64 + m * 16 + l15;
                int off = r * 64 + (((ks * 4 + lhi) ^ (r & 7)) * 8);
                ah[m] = *(const short8*)&LAh[off];
                al[m] = *(const short8*)&LAl[off];
            }
#pragma unroll
            for (int n = 0; n < 4; ++n) {
                int r = wn * 64 + n * 16 + l15;
                int off = r * 64 + (((ks * 4 + lhi) ^ (r & 7)) * 8);
                bh[n] = *(const short8*)&LBh[off];
                bl[n] = *(const short8*)&LBl[off];
            }
#pragma unroll
            for (int m = 0; m < 4; ++m)
#pragma unroll
                for (int n = 0; n < 4; ++n) {
                    acc[m][n] = __builtin_amdgcn_mfma_f32_16x16x32_bf16(ah[m], bh[n], acc[m][n], 0, 0, 0);
                    acc[m][n] = __builtin_amdgcn_mfma_f32_16x16x32_bf16(ah[m], bl[n], acc[m][n], 0, 0, 0);
                    acc[m][n] = __builtin_amdgcn_mfma_f32_16x16x32_bf16(al[m], bh[n], acc[m][n], 0, 0, 0);
                }
        }
        __syncthreads();
    }
}

// ---------------------------------------------------------------------------
// Wg_w = W_w @ g_w  (fp32, small: 0.27 GFLOP)
// ---------------------------------------------------------------------------
#define TS 64
#define KS 16
__global__ __launch_bounds__(256) void k_gemm_nn(const float* __restrict__ A,
                                                 const float* __restrict__ B,
                                                 float* __restrict__ C,
                                                 int M, int N, int K) {
    __shared__ float As[TS][KS + 1];
    __shared__ float Bs[KS][TS];
    int tid = threadIdx.x;
    int tx = tid & 15, ty = tid >> 4;
    int i0 = blockIdx.y * TS, j0 = blockIdx.x * TS;
    float acc[4][4] = {};
    for (int k0 = 0; k0 < K; k0 += KS) {
        {
            int c = tid & 15, r0 = tid >> 4;
#pragma unroll
            for (int l = 0; l < 4; ++l) As[r0 + l * 16][c] = A[(i0 + r0 + l * 16) * K + k0 + c];
        }
        {
            int j = tid & 63, r0 = tid >> 6;
#pragma unroll
            for (int l = 0; l < 4; ++l) Bs[r0 + l * 4][j] = B[(k0 + r0 + l * 4) * N + j0 + j];
        }
        __syncthreads();
#pragma unroll
        for (int kk = 0; kk < KS; ++kk) {
            float4 b4 = *(const float4*)&Bs[kk][tx * 4];
#pragma unroll
            for (int i = 0; i < 4; ++i) {
                float a = As[ty * 4 + i][kk];
                acc[i][0] += a * b4.x; acc[i][1] += a * b4.y;
                acc[i][2] += a * b4.z; acc[i][3] += a * b4.w;
            }
        }
        __syncthreads();
    }
#pragma unroll
    for (int i = 0; i < 4; ++i) {
        float4 v = {acc[i][0], acc[i][1], acc[i][2], acc[i][3]};
        *(float4*)&C[(i0 + ty * 4 + i) * N + j0 + tx * 4] = v;
    }
}

// ---------------------------------------------------------------------------
// Split fp32 weight matrices into bf16 hi/lo. grid (256, 5), block 256.
// ---------------------------------------------------------------------------
__global__ __launch_bounds__(256) void k_split_w(
    const float* __restrict__ tw, const float* __restrict__ fw,
    const float* __restrict__ wgw, const float* __restrict__ p1w,
    const float* __restrict__ p2w, unsigned short* __restrict__ Whi,
    unsigned short* __restrict__ Wlo, unsigned short* __restrict__ p1h,
    unsigned short* __restrict__ p1l, unsigned short* __restrict__ p2h,
    unsigned short* __restrict__ p2l) {
    int z = blockIdx.y;
    const float* src = (z == 0) ? tw : (z == 1) ? fw : (z == 2) ? wgw : (z == 3) ? p1w : p2w;
    unsigned short* dh = (z < 3) ? Whi + z * 262144 : ((z == 3) ? p1h : p2h);
    unsigned short* dl = (z < 3) ? Wlo + z * 262144 : ((z == 3) ? p1l : p2l);
    int i4 = blockIdx.x * 256 + threadIdx.x;
    float4v v = ((const float4v*)src)[i4];
    ushort4v h, l;
#pragma unroll
    for (int j = 0; j < 4; ++j) {
        h[j] = f2bf(v[j]);
        l[j] = f2bf(v[j] - bf2f(h[j]));
    }
    ((ushort4v*)dh)[i4] = h;
    ((ushort4v*)dl)[i4] = l;
}

// ---------------------------------------------------------------------------
// Transpose+split inputs: Xt[((b*128+t)*3+k)*512 + c] = in_k[b][c][t] (hi/lo)
// ---------------------------------------------------------------------------
__global__ __launch_bounds__(256) void k_splitx(const float* __restrict__ o1,
                                                const float* __restrict__ o2,
                                                const float* __restrict__ o3,
                                                unsigned short* __restrict__ Xh,
                                                unsigned short* __restrict__ Xl) {
    int z = blockIdx.z;
    int b = z / 3, k = z - b * 3;
    const float* In = (k == 0) ? o1 : ((k == 1) ? o2 : o3);
    int c0 = blockIdx.x * 32, t0 = blockIdx.y * 32;
    __shared__ float tile[32][33];
    int tx = threadIdx.x, ty = threadIdx.y;
#pragma unroll
    for (int i = 0; i < 4; ++i)
        tile[ty + i * 8][tx] = In[(b * 512 + c0 + ty + i * 8) * 128 + t0 + tx];
    __syncthreads();
#pragma unroll
    for (int i = 0; i < 4; ++i) {
        int t = t0 + ty + i * 8;
        float v = tile[tx][ty + i * 8];
        unsigned short h = f2bf(v), l = f2bf(v - bf2f(h));
        int idx = ((b * 128 + t) * 3 + k) * 512 + c0 + tx;
        Xh[idx] = h;
        Xl[idx] = l;
    }
}

// ---------------------------------------------------------------------------
// Stage A via MFMA: grid (48, 12): x = b*3+kin, y = o-tile (wsel = y>>2)
// ---------------------------------------------------------------------------
__global__ __launch_bounds__(256) void k_ga(
    const unsigned short* __restrict__ Whi, const unsigned short* __restrict__ Wlo,
    const unsigned short* __restrict__ Xh, const unsigned short* __restrict__ Xl,
    unsigned short* __restrict__ Thh, unsigned short* __restrict__ Thl,
    unsigned short* __restrict__ Phh, unsigned short* __restrict__ Phl,
    float* __restrict__ Wg) {
    __shared__ unsigned short lds[32768];
    int bk = blockIdx.x, y = blockIdx.y;
    int b = bk / 3, kin = bk - b * 3;
    int bbase = (b * 384 + kin) * 512;
    float4v acc[4][4];
#pragma unroll
    for (int m = 0; m < 4; ++m)
#pragma unroll
        for (int n = 0; n < 4; ++n) acc[m][n] = (float4v){0.f, 0.f, 0.f, 0.f};

    mfma_core(Whi + y * 128 * 512, Wlo + y * 128 * 512, 512,
              Xh + bbase, Xl + bbase, 1536, lds, acc);

    int lane = threadIdx.x & 63, wave = threadIdx.x >> 6;
    int wm = wave >> 1, wn = wave & 1, l15 = lane & 15, lhi = lane >> 4;
    int wsel = y >> 2, o0 = (y & 3) * 128;
#pragma unroll
    for (int m = 0; m < 4; ++m)
#pragma unroll
        for (int n = 0; n < 4; ++n) {
            int o_in = wm * 64 + m * 16 + lhi * 4;
            int t = wn * 64 + n * 16 + l15;
            int idx = bbase + t * 1536 + o0 + o_in;
            if (wsel == 2) {
                *(float4v*)&Wg[idx] = acc[m][n];
            } else {
                ushort4v h, l;
#pragma unroll
                for (int i = 0; i < 4; ++i) {
                    float v = acc[m][n][i];
                    h[i] = f2bf(v);
                    l[i] = f2bf(v - bf2f(h[i]));
                }
                unsigned short* dh = wsel ? Phh : Thh;
                unsigned short* dl = wsel ? Phl : Thl;
                *(ushort4v*)&dh[idx] = h;
                *(ushort4v*)&dl[idx] = l;
            }
        }
}

// ---------------------------------------------------------------------------
// Gram via MFMA. grid 144, XCD-swizzled so same-b mats share an XCD's L2.
// ---------------------------------------------------------------------------
__global__ __launch_bounds__(256) void k_gram2(
    const unsigned short* __restrict__ Thh, const unsigned short* __restrict__ Thl,
    const unsigned short* __restrict__ Phh, const unsigned short* __restrict__ Phl,
    float* __restrict__ D) {
    __shared__ unsigned short lds[32768];
    int orig = blockIdx.x;
    int mat = (orig & 7) * 18 + (orig >> 3);  // 144 = 8 * 18, bijective
    int b = mat / 9, r9 = mat - b * 9, k = r9 / 3, kp = r9 - k * 3;
    int Ab = (b * 384 + k) * 512, Bb = (b * 384 + kp) * 512;
    float4v acc[4][4];
#pragma unroll
    for (int m = 0; m < 4; ++m)
#pragma unroll
        for (int n = 0; n < 4; ++n) acc[m][n] = (float4v){0.f, 0.f, 0.f, 0.f};

    mfma_core(Thh + Ab, Thl + Ab, 1536, Phh + Bb, Phl + Bb, 1536, lds, acc);

    int lane = threadIdx.x & 63, wave = threadIdx.x >> 6;
    int wm = wave >> 1, wn = wave & 1, l15 = lane & 15, lhi = lane >> 4;
    float* Dm = D + mat * 16384;
#pragma unroll
    for (int m = 0; m < 4; ++m)
#pragma unroll
        for (int n = 0; n < 4; ++n) {
            int t2 = wn * 64 + n * 16 + l15;
#pragma unroll
            for (int i = 0; i < 4; ++i) {
                int t1 = wm * 64 + m * 16 + lhi * 4 + i;
                Dm[t1 * 128 + t2] = acc[m][n][i];
            }
        }
}

// ---------------------------------------------------------------------------
// MLP layer via MFMA: C[r][o] = lrelu( A[r,:] . W[o,:] )
// ---------------------------------------------------------------------------
template <bool SPLIT_OUT>
__global__ __launch_bounds__(256) void k_mlp(
    const unsigned short* __restrict__ Ahi, const unsigned short* __restrict__ Alo,
    const unsigned short* __restrict__ Bhi, const unsigned short* __restrict__ Blo,
    unsigned short* __restrict__ Ch, unsigned short* __restrict__ Cl,
    float* __restrict__ Cf) {
    __shared__ unsigned short lds[32768];
    int r0 = blockIdx.x * 128, o0 = blockIdx.y * 128;
    float4v acc[4][4];
#pragma unroll
    for (int m = 0; m < 4; ++m)
#pragma unroll
        for (int n = 0; n < 4; ++n) acc[m][n] = (float4v){0.f, 0.f, 0.f, 0.f};

    mfma_core(Ahi + r0 * 512, Alo + r0 * 512, 512, Bhi + o0 * 512, Blo + o0 * 512, 512, lds, acc);

    int lane = threadIdx.x & 63, wave = threadIdx.x >> 6;
    int wm = wave >> 1, wn = wave & 1, l15 = lane & 15, lhi = lane >> 4;
#pragma unroll
    for (int m = 0; m < 4; ++m)
#pragma unroll
        for (int n = 0; n < 4; ++n) {
            int o = o0 + wn * 64 + n * 16 + l15;
#pragma unroll
            for (int i = 0; i < 4; ++i) {
                int r = r0 + wm * 64 + m * 16 + lhi * 4 + i;
                float v = lrelu(acc[m][n][i]);
                if (SPLIT_OUT) {
                    unsigned short h = f2bf(v), l = f2bf(v - bf2f(h));
                    Ch[r * 512 + o] = h;
                    Cl[r * 512 + o] = l;
                } else {
                    Cf[r * 512 + o] = v;
                }
            }
        }
}

// ---------------------------------------------------------------------------
// Mix (round-4 proven body: 54us, 36 VGPR, no spill): per (b,t): gather f
// from D, softmax rows, then one o per thread with wg[24]/xw[24] preloads.
// grid 2048, block 512.
// ---------------------------------------------------------------------------
__global__ __launch_bounds__(512) void k_mix(
    const unsigned short* __restrict__ Xh, const unsigned short* __restrict__ Xl,
    const float* __restrict__ Wg, const float* __restrict__ D,
    const float* __restrict__ W_b, unsigned short* __restrict__ Plh,
    unsigned short* __restrict__ Pll) {
    int bid = blockIdx.x;
    int b = bid >> 7, t = bid & 127;
    int tid = threadIdx.x;

    __shared__ float Pm[24][28];

    for (int idx = tid; idx < 576; idx += 512) {
        int n = idx / 24, m = idx - n * 24;
        int j = n / 3, k = n - j * 3;
        int jp = m / 3, kp = m - jp * 3;
        int t1 = t - 7 + j, t2 = t - 7 + jp;
        float v = 0.f;
        if (t1 >= 0 && t2 >= 0)
            v = D[((((b * 3 + k) * 3 + kp) * 128 + t1) << 7) + t2];
        Pm[n][m] = v;
    }
    __syncthreads();

    if (tid < 24) {
        float mx = -1e30f;
#pragma unroll
        for (int m = 0; m < 24; ++m) mx = fmaxf(mx, Pm[tid][m]);
        float e[24], sum = 0.f;
#pragma unroll
        for (int m = 0; m < 24; ++m) { e[m] = __expf(Pm[tid][m] - mx); sum += e[m]; }
        float inv = 1.0f / sum;
#pragma unroll
        for (int m = 0; m < 24; ++m) Pm[tid][m] = e[m] * inv;
    }
    __syncthreads();

    int o = tid;
    float wg[24], xw[24];
#pragma unroll
    for (int m = 0; m < 24; ++m) {
        int j = m / 3, k = m - j * 3;
        int tp = t - 7 + j;
        int base = (((b * 128 + tp) * 3 + k) << 9) + o;
        wg[m] = (tp >= 0) ? Wg[base] : 0.f;
        xw[m] = (tp >= 0) ? (bf2f(Xh[base]) + bf2f(Xl[base])) : 0.f;
    }
    float wb = W_b[o];
    float pooled = -1e30f;
#pragma unroll
    for (int n = 0; n < 24; ++n) {
        float s = 0.f;
#pragma unroll
        for (int m = 0; m < 24; ++m) s += Pm[n][m] * wg[m];
        s += wb + xw[n];
        pooled = fmaxf(pooled, s);
    }
    int oidx = ((t * 16 + b) << 9) + o;
    unsigned short h = f2bf(pooled), l = f2bf(pooled - bf2f(h));
    Plh[oidx] = h;
    Pll[oidx] = l;
}

// ---------------------------------------------------------------------------
// out[r] = lrelu( sum_c H[r][c]*p3w[c] + p3b )   one wave per row
// ---------------------------------------------------------------------------
__global__ __launch_bounds__(256) void k_final(const float* __restrict__ H,
                                               const float* __restrict__ p3w,
                                               const float* __restrict__ p3b,
                                               float* __restrict__ out) {
    int r = blockIdx.x * 4 + (threadIdx.x >> 6);
    int lane = threadIdx.x & 63;
    const float4* h4 = (const float4*)&H[r << 9];
    const float4* w4 = (const float4*)p3w;
    float4 a1 = h4[lane], a2 = h4[lane + 64];
    float4 b1 = w4[lane], b2 = w4[lane + 64];
    float s = a1.x * b1.x + a1.y * b1.y + a1.z * b1.z + a1.w * b1.w +
              a2.x * b2.x + a2.y * b2.y + a2.z * b2.z + a2.w * b2.w;
#pragma unroll
    for (int off = 32; off; off >>= 1) s += __shfl_down(s, off, 64);
    if (lane == 0) out[r] = lrelu(s + p3b[0]);
}

extern "C" void kernel_launch(void* const* d_in, const int* in_sizes, int n_in,
                              void* d_out, int out_size, void* d_ws, size_t ws_size,
                              hipStream_t stream) {
    const float* out1 = (const float*)d_in[0];
    const float* out2 = (const float*)d_in[1];
    const float* out3 = (const float*)d_in[2];
    const float* theta_w = (const float*)d_in[3];
    const float* phi_w = (const float*)d_in[4];
    const float* g_w = (const float*)d_in[5];
    const float* W_w = (const float*)d_in[6];
    const float* W_b = (const float*)d_in[7];
    const float* p1_w = (const float*)d_in[8];
    const float* p2_w = (const float*)d_in[9];
    const float* p3_w = (const float*)d_in[10];
    const float* p3_b = (const float*)d_in[11];
    float* outp = (float*)d_out;

    // ---- workspace layout (bytes) ----
    char* wsb = (char*)d_ws;
    float* Wg_w = (float*)(wsb + 0);
    unsigned short* Whi = (unsigned short*)(wsb + 1048576);
    unsigned short* Wlo = (unsigned short*)(wsb + 2621440);
    unsigned short* p1h = (unsigned short*)(wsb + 4194304);
    unsigned short* p1l = (unsigned short*)(wsb + 4718592);
    unsigned short* p2h = (unsigned short*)(wsb + 5242880);
    unsigned short* p2l = (unsigned short*)(wsb + 5767168);
    unsigned short* Xh  = (unsigned short*)(wsb + 6291456);
    unsigned short* Xl  = (unsigned short*)(wsb + 12582912);
    unsigned short* Thh = (unsigned short*)(wsb + 18874368);
    unsigned short* Thl = (unsigned short*)(wsb + 25165824);
    unsigned short* Phh = (unsigned short*)(wsb + 31457280);
    unsigned short* Phl = (unsigned short*)(wsb + 37748736);
    float* Wg = (float*)(wsb + 44040192);
    float* D  = (float*)(wsb + 56623104);
    // aliases (dead-buffer reuse):
    unsigned short* Plh = (unsigned short*)(wsb + 31457280);  // over Phh
    unsigned short* Pll = (unsigned short*)(wsb + 33554432);
    unsigned short* h1h = (unsigned short*)(wsb + 18874368);  // over Thh
    unsigned short* h1l = (unsigned short*)(wsb + 20971520);
    float* h2 = (float*)(wsb + 23068672);

    k_gemm_nn<<<dim3(8, 8), 256, 0, stream>>>(W_w, g_w, Wg_w, 512, 512, 512);
    k_split_w<<<dim3(256, 5), 256, 0, stream>>>(theta_w, phi_w, Wg_w, p1_w, p2_w,
                                                Whi, Wlo, p1h, p1l, p2h, p2l);
    k_splitx<<<dim3(16, 4, 48), dim3(32, 8), 0, stream>>>(out1, out2, out3, Xh, Xl);
    k_ga<<<dim3(48, 12), 256, 0, stream>>>(Whi, Wlo, Xh, Xl, Thh, Thl, Phh, Phl, Wg);
    k_gram2<<<dim3(144), 256, 0, stream>>>(Thh, Thl, Phh, Phl, D);
    k_mix<<<dim3(2048), 512, 0, stream>>>(Xh, Xl, Wg, D, W_b, Plh, Pll);
    k_mlp<true><<<dim3(16, 4), 256, 0, stream>>>(Plh, Pll, p1h, p1l, h1h, h1l, nullptr);
    k_mlp<false><<<dim3(16, 4), 256, 0, stream>>>(h1h, h1l, p2h, p2l, nullptr, nullptr, h2);
    k_final<<<dim3(512), 256, 0, stream>>>(h2, p3_w, p3_b, outp);
}

// Round 7
// 180.813 us; speedup vs baseline: 4.4227x; 1.1034x over previous
//
#include <hip/hip_runtime.h>

typedef __attribute__((ext_vector_type(8))) short short8;
typedef __attribute__((ext_vector_type(4))) float float4v;
typedef __attribute__((ext_vector_type(4))) unsigned int uint4v;
typedef __attribute__((ext_vector_type(4))) unsigned short ushort4v;

__device__ __forceinline__ float lrelu(float v) { return v >= 0.f ? v : 0.01f * v; }

__device__ __forceinline__ unsigned short f2bf(float x) {
    union { float f; unsigned u; } c; c.f = x;
    unsigned r = (c.u + 0x7FFFu + ((c.u >> 16) & 1u)) >> 16;
    return (unsigned short)r;
}
__device__ __forceinline__ float bf2f(unsigned short h) {
    union { unsigned u; float f; } c; c.u = ((unsigned)h) << 16;
    return c.f;
}

// async global->LDS, 16B per lane. LDS dest must be wave-uniform base
// (HW adds lane*16); global src is per-lane (pre-swizzled).
__device__ __forceinline__ void gload16(const unsigned short* g, unsigned short* l) {
    __builtin_amdgcn_global_load_lds(
        (const __attribute__((address_space(1))) unsigned int*)g,
        (__attribute__((address_space(3))) unsigned int*)l, 16, 0, 0);
}

// ===========================================================================
// Shared MFMA core: C[128x128] += A[128xK] * B[128xK]^T, K=512, split-bf16
// (hi*hi + hi*lo + lo*hi -> ~fp32 precision). 256 threads, 4 waves 2x2.
// LDS: 4 tiles [128][64] bf16. global_load_lds direct staging: LDS linear,
// global source pre-swizzled with the same XOR involution the reads use.
// ===========================================================================
__device__ __forceinline__ void mfma_core(
    const unsigned short* __restrict__ Ah, const unsigned short* __restrict__ Al, int lda,
    const unsigned short* __restrict__ Bh, const unsigned short* __restrict__ Bl, int ldb,
    unsigned short* lds, float4v acc[4][4]) {
    const int tid = threadIdx.x;
    const int lane = tid & 63, wave = tid >> 6;
    const int wm = wave >> 1, wn = wave & 1;
    const int l15 = lane & 15, lhi = lane >> 4;
    unsigned short* LAh = lds;
    unsigned short* LAl = lds + 8192;
    unsigned short* LBh = lds + 16384;
    unsigned short* LBl = lds + 24576;

    for (int k0 = 0; k0 < 512; k0 += 64) {
#pragma unroll
        for (int tile = 0; tile < 4; ++tile) {
            const unsigned short* s = (tile == 0) ? Ah : (tile == 1) ? Al : (tile == 2) ? Bh : Bl;
            int ld = (tile < 2) ? lda : ldb;
            unsigned short* dbase = lds + tile * 8192;
#pragma unroll
            for (int it = 0; it < 4; ++it) {
                int idx = it * 256 + tid;
                int row = idx >> 3, ch = idx & 7;
                // linear LDS dest (wave-uniform base), swizzled global src
                gload16(&s[row * ld + k0 + ((ch ^ (row & 7)) << 3)],
                        dbase + ((it * 256 + wave * 64) << 3));
            }
        }
        __syncthreads();
#pragma unroll
        for (int ks = 0; ks < 2; ++ks) {
            short8 ah[4], al[4], bh[4], bl[4];
#pragma unroll
            for (int m = 0; m < 4; ++m) {
                int r = wm * 64 + m * 16 + l15;
                int off = r * 64 + (((ks * 4 + lhi) ^ (r & 7)) * 8);
                ah[m] = *(const short8*)&LAh[off];
                al[m] = *(const short8*)&LAl[off];
            }
#pragma unroll
            for (int n = 0; n < 4; ++n) {
                int r = wn * 64 + n * 16 + l15;
                int off = r * 64 + (((ks * 4 + lhi) ^ (r & 7)) * 8);
                bh[n] = *(const short8*)&LBh[off];
                bl[n] = *(const short8*)&LBl[off];
            }
#pragma unroll
            for (int m = 0; m < 4; ++m)
#pragma unroll
                for (int n = 0; n < 4; ++n) {
                    acc[m][n] = __builtin_amdgcn_mfma_f32_16x16x32_bf16(ah[m], bh[n], acc[m][n], 0, 0, 0);
                    acc[m][n] = __builtin_amdgcn_mfma_f32_16x16x32_bf16(ah[m], bl[n], acc[m][n], 0, 0, 0);
                    acc[m][n] = __builtin_amdgcn_mfma_f32_16x16x32_bf16(al[m], bh[n], acc[m][n], 0, 0, 0);
                }
        }
        __syncthreads();
    }
}

// ---------------------------------------------------------------------------
// Two small fp32 512x512x512 GEMMs in one launch (grid.z):
//   z=0: Wg_w = W_w @ g_w          (C[i][j] = sum_k A[i][k] B[k][j])
//   z=1: Mw   = theta_w^T @ phi_w  (C[i][j] = sum_k A[k][i] B[k][j])
// ---------------------------------------------------------------------------
#define TS 64
#define KS 16
__global__ __launch_bounds__(256) void k_gemm2(
    const float* __restrict__ Aw, const float* __restrict__ Bw, float* __restrict__ Cw,
    const float* __restrict__ At, const float* __restrict__ Bt, float* __restrict__ Ct) {
    const bool tr = blockIdx.z != 0;
    const float* A = tr ? At : Aw;
    const float* B = tr ? Bt : Bw;
    float* C = tr ? Ct : Cw;
    __shared__ float As[TS][KS + 1];
    __shared__ float Bs[KS][TS];
    int tid = threadIdx.x;
    int tx = tid & 15, ty = tid >> 4;
    int i0 = blockIdx.y * TS, j0 = blockIdx.x * TS;
    float acc[4][4] = {};
    for (int k0 = 0; k0 < 512; k0 += KS) {
        {
            int c = tid & 15, r0 = tid >> 4;
#pragma unroll
            for (int l = 0; l < 4; ++l) {
                int r = r0 + l * 16;
                As[r][c] = tr ? A[(k0 + c) * 512 + i0 + r] : A[(i0 + r) * 512 + k0 + c];
            }
        }
        {
            int j = tid & 63, r0 = tid >> 6;
#pragma unroll
            for (int l = 0; l < 4; ++l) Bs[r0 + l * 4][j] = B[(k0 + r0 + l * 4) * 512 + j0 + j];
        }
        __syncthreads();
#pragma unroll
        for (int kk = 0; kk < KS; ++kk) {
            float4 b4 = *(const float4*)&Bs[kk][tx * 4];
#pragma unroll
            for (int i = 0; i < 4; ++i) {
                float a = As[ty * 4 + i][kk];
                acc[i][0] += a * b4.x; acc[i][1] += a * b4.y;
                acc[i][2] += a * b4.z; acc[i][3] += a * b4.w;
            }
        }
        __syncthreads();
    }
#pragma unroll
    for (int i = 0; i < 4; ++i) {
        float4 v = {acc[i][0], acc[i][1], acc[i][2], acc[i][3]};
        *(float4*)&C[(i0 + ty * 4 + i) * 512 + j0 + tx * 4] = v;
    }
}

// ---------------------------------------------------------------------------
// Split fp32 weight matrices into bf16 hi/lo. grid (256, 4), block 256.
// z: 0=Mw -> Whi rows 0-511, 1=Wg_w -> rows 512-1023, 2=p1_w, 3=p2_w
// ---------------------------------------------------------------------------
__global__ __launch_bounds__(256) void k_split_w(
    const float* __restrict__ mw, const float* __restrict__ wgw,
    const float* __restrict__ p1w, const float* __restrict__ p2w,
    unsigned short* __restrict__ Whi, unsigned short* __restrict__ Wlo,
    unsigned short* __restrict__ p1h, unsigned short* __restrict__ p1l,
    unsigned short* __restrict__ p2h, unsigned short* __restrict__ p2l) {
    int z = blockIdx.y;
    const float* src = (z == 0) ? mw : (z == 1) ? wgw : (z == 2) ? p1w : p2w;
    unsigned short* dh = (z < 2) ? Whi + z * 262144 : ((z == 2) ? p1h : p2h);
    unsigned short* dl = (z < 2) ? Wlo + z * 262144 : ((z == 2) ? p1l : p2l);
    int i4 = blockIdx.x * 256 + threadIdx.x;
    float4v v = ((const float4v*)src)[i4];
    ushort4v h, l;
#pragma unroll
    for (int j = 0; j < 4; ++j) {
        h[j] = f2bf(v[j]);
        l[j] = f2bf(v[j] - bf2f(h[j]));
    }
    ((ushort4v*)dh)[i4] = h;
    ((ushort4v*)dl)[i4] = l;
}

// ---------------------------------------------------------------------------
// Transpose+split inputs: Xt[((b*128+t)*3+k)*512 + c] = in_k[b][c][t] (hi/lo)
// ---------------------------------------------------------------------------
__global__ __launch_bounds__(256) void k_splitx(const float* __restrict__ o1,
                                                const float* __restrict__ o2,
                                                const float* __restrict__ o3,
                                                unsigned short* __restrict__ Xh,
                                                unsigned short* __restrict__ Xl) {
    int z = blockIdx.z;
    int b = z / 3, k = z - b * 3;
    const float* In = (k == 0) ? o1 : ((k == 1) ? o2 : o3);
    int c0 = blockIdx.x * 32, t0 = blockIdx.y * 32;
    __shared__ float tile[32][33];
    int tx = threadIdx.x, ty = threadIdx.y;
#pragma unroll
    for (int i = 0; i < 4; ++i)
        tile[ty + i * 8][tx] = In[(b * 512 + c0 + ty + i * 8) * 128 + t0 + tx];
    __syncthreads();
#pragma unroll
    for (int i = 0; i < 4; ++i) {
        int t = t0 + ty + i * 8;
        float v = tile[tx][ty + i * 8];
        unsigned short h = f2bf(v), l = f2bf(v - bf2f(h));
        int idx = ((b * 128 + t) * 3 + k) * 512 + c0 + tx;
        Xh[idx] = h;
        Xl[idx] = l;
    }
}

// ---------------------------------------------------------------------------
// Stage A via MFMA: grid (48, 8): x = b*3+kin, y = o-tile
//   y 0-3 -> Y = Mw . x (bf16 hi/lo), y 4-7 -> Wg = Wg_w . x (fp32)
// ---------------------------------------------------------------------------
__global__ __launch_bounds__(256) void k_ga(
    const unsigned short* __restrict__ Whi, const unsigned short* __restrict__ Wlo,
    const unsigned short* __restrict__ Xh, const unsigned short* __restrict__ Xl,
    unsigned short* __restrict__ Yh, unsigned short* __restrict__ Yl,
    float* __restrict__ Wg) {
    __shared__ unsigned short lds[32768];
    int bk = blockIdx.x, y = blockIdx.y;
    int b = bk / 3, kin = bk - b * 3;
    int bbase = (b * 384 + kin) * 512;
    float4v acc[4][4];
#pragma unroll
    for (int m = 0; m < 4; ++m)
#pragma unroll
        for (int n = 0; n < 4; ++n) acc[m][n] = (float4v){0.f, 0.f, 0.f, 0.f};

    mfma_core(Whi + y * 128 * 512, Wlo + y * 128 * 512, 512,
              Xh + bbase, Xl + bbase, 1536, lds, acc);

    int lane = threadIdx.x & 63, wave = threadIdx.x >> 6;
    int wm = wave >> 1, wn = wave & 1, l15 = lane & 15, lhi = lane >> 4;
    int wsel = y >> 2, o0 = (y & 3) * 128;
#pragma unroll
    for (int m = 0; m < 4; ++m)
#pragma unroll
        for (int n = 0; n < 4; ++n) {
            int o_in = wm * 64 + m * 16 + lhi * 4;
            int t = wn * 64 + n * 16 + l15;
            int idx = bbase + t * 1536 + o0 + o_in;
            if (wsel == 1) {
                *(float4v*)&Wg[idx] = acc[m][n];
            } else {
                ushort4v h, l;
#pragma unroll
                for (int i = 0; i < 4; ++i) {
                    float v = acc[m][n][i];
                    h[i] = f2bf(v);
                    l[i] = f2bf(v - bf2f(h[i]));
                }
                *(ushort4v*)&Yh[idx] = h;
                *(ushort4v*)&Yl[idx] = l;
            }
        }
}

// ---------------------------------------------------------------------------
// Gram via MFMA: D[mat][t1][t2] = X[b,t1,k,:] . Y[b,t2,kp,:]
// grid 144, XCD-swizzled so same-b mats share an XCD's L2.
// ---------------------------------------------------------------------------
__global__ __launch_bounds__(256) void k_gram2(
    const unsigned short* __restrict__ Xh, const unsigned short* __restrict__ Xl,
    const unsigned short* __restrict__ Yh, const unsigned short* __restrict__ Yl,
    float* __restrict__ D) {
    __shared__ unsigned short lds[32768];
    int orig = blockIdx.x;
    int mat = (orig & 7) * 18 + (orig >> 3);  // 144 = 8 * 18, bijective
    int b = mat / 9, r9 = mat - b * 9, k = r9 / 3, kp = r9 - k * 3;
    int Ab = (b * 384 + k) * 512, Bb = (b * 384 + kp) * 512;
    float4v acc[4][4];
#pragma unroll
    for (int m = 0; m < 4; ++m)
#pragma unroll
        for (int n = 0; n < 4; ++n) acc[m][n] = (float4v){0.f, 0.f, 0.f, 0.f};

    mfma_core(Xh + Ab, Xl + Ab, 1536, Yh + Bb, Yl + Bb, 1536, lds, acc);

    int lane = threadIdx.x & 63, wave = threadIdx.x >> 6;
    int wm = wave >> 1, wn = wave & 1, l15 = lane & 15, lhi = lane >> 4;
    float* Dm = D + mat * 16384;
#pragma unroll
    for (int m = 0; m < 4; ++m)
#pragma unroll
        for (int n = 0; n < 4; ++n) {
            int t2 = wn * 64 + n * 16 + l15;
#pragma unroll
            for (int i = 0; i < 4; ++i) {
                int t1 = wm * 64 + m * 16 + lhi * 4 + i;
                Dm[t1 * 128 + t2] = acc[m][n][i];
            }
        }
}

// ---------------------------------------------------------------------------
// MLP layer via MFMA: C[r][o] = lrelu( A[r,:] . W[o,:] )
// ---------------------------------------------------------------------------
template <bool SPLIT_OUT>
__global__ __launch_bounds__(256) void k_mlp(
    const unsigned short* __restrict__ Ahi, const unsigned short* __restrict__ Alo,
    const unsigned short* __restrict__ Bhi, const unsigned short* __restrict__ Blo,
    unsigned short* __restrict__ Ch, unsigned short* __restrict__ Cl,
    float* __restrict__ Cf) {
    __shared__ unsigned short lds[32768];
    int r0 = blockIdx.x * 128, o0 = blockIdx.y * 128;
    float4v acc[4][4];
#pragma unroll
    for (int m = 0; m < 4; ++m)
#pragma unroll
        for (int n = 0; n < 4; ++n) acc[m][n] = (float4v){0.f, 0.f, 0.f, 0.f};

    mfma_core(Ahi + r0 * 512, Alo + r0 * 512, 512, Bhi + o0 * 512, Blo + o0 * 512, 512, lds, acc);

    int lane = threadIdx.x & 63, wave = threadIdx.x >> 6;
    int wm = wave >> 1, wn = wave & 1, l15 = lane & 15, lhi = lane >> 4;
#pragma unroll
    for (int m = 0; m < 4; ++m)
#pragma unroll
        for (int n = 0; n < 4; ++n) {
            int o = o0 + wn * 64 + n * 16 + l15;
#pragma unroll
            for (int i = 0; i < 4; ++i) {
                int r = r0 + wm * 64 + m * 16 + lhi * 4 + i;
                float v = lrelu(acc[m][n][i]);
                if (SPLIT_OUT) {
                    unsigned short h = f2bf(v), l = f2bf(v - bf2f(h));
                    Ch[r * 512 + o] = h;
                    Cl[r * 512 + o] = l;
                } else {
                    Cf[r * 512 + o] = v;
                }
            }
        }
}

// ---------------------------------------------------------------------------
// Mix (round-4 proven body, + XCD swizzle only): per (b,t): gather f from D,
// softmax rows, one o per thread with wg[24]/xw[24] preloads.
// grid 2048 (XCD r gets bids [r*256,(r+1)*256) = exactly 2 b's), block 512.
// ---------------------------------------------------------------------------
__global__ __launch_bounds__(512) void k_mix(
    const unsigned short* __restrict__ Xh, const unsigned short* __restrict__ Xl,
    const float* __restrict__ Wg, const float* __restrict__ D,
    const float* __restrict__ W_b, unsigned short* __restrict__ Plh,
    unsigned short* __restrict__ Pll) {
    int orig = blockIdx.x;
    int bid = ((orig & 7) << 8) | (orig >> 3);  // 2048 = 8 * 256, bijective
    int b = bid >> 7, t = bid & 127;
    int tid = threadIdx.x;

    __shared__ float Pm[24][28];

    for (int idx = tid; idx < 576; idx += 512) {
        int n = idx / 24, m = idx - n * 24;
        int j = n / 3, k = n - j * 3;
        int jp = m / 3, kp = m - jp * 3;
        int t1 = t - 7 + j, t2 = t - 7 + jp;
        float v = 0.f;
        if (t1 >= 0 && t2 >= 0)
            v = D[((((b * 3 + k) * 3 + kp) * 128 + t1) << 7) + t2];
        Pm[n][m] = v;
    }
    __syncthreads();

    if (tid < 24) {
        float mx = -1e30f;
#pragma unroll
        for (int m = 0; m < 24; ++m) mx = fmaxf(mx, Pm[tid][m]);
        float e[24], sum = 0.f;
#pragma unroll
        for (int m = 0; m < 24; ++m) { e[m] = __expf(Pm[tid][m] - mx); sum += e[m]; }
        float inv = 1.0f / sum;
#pragma unroll
        for (int m = 0; m < 24; ++m) Pm[tid][m] = e[m] * inv;
    }
    __syncthreads();

    int o = tid;
    float wg[24], xw[24];
#pragma unroll
    for (int m = 0; m < 24; ++m) {
        int j = m / 3, k = m - j * 3;
        int tp = t - 7 + j;
        int base = (((b * 128 + tp) * 3 + k) << 9) + o;
        wg[m] = (tp >= 0) ? Wg[base] : 0.f;
        xw[m] = (tp >= 0) ? (bf2f(Xh[base]) + bf2f(Xl[base])) : 0.f;
    }
    float wb = W_b[o];
    float pooled = -1e30f;
#pragma unroll
    for (int n = 0; n < 24; ++n) {
        float s = 0.f;
#pragma unroll
        for (int m = 0; m < 24; ++m) s += Pm[n][m] * wg[m];
        s += wb + xw[n];
        pooled = fmaxf(pooled, s);
    }
    int oidx = ((t * 16 + b) << 9) + o;
    unsigned short h = f2bf(pooled), l = f2bf(pooled - bf2f(h));
    Plh[oidx] = h;
    Pll[oidx] = l;
}

// ---------------------------------------------------------------------------
// out[r] = lrelu( sum_c H[r][c]*p3w[c] + p3b )   one wave per row
// ---------------------------------------------------------------------------
__global__ __launch_bounds__(256) void k_final(const float* __restrict__ H,
                                               const float* __restrict__ p3w,
                                               const float* __restrict__ p3b,
                                               float* __restrict__ out) {
    int r = blockIdx.x * 4 + (threadIdx.x >> 6);
    int lane = threadIdx.x & 63;
    const float4* h4 = (const float4*)&H[r << 9];
    const float4* w4 = (const float4*)p3w;
    float4 a1 = h4[lane], a2 = h4[lane + 64];
    float4 b1 = w4[lane], b2 = w4[lane + 64];
    float s = a1.x * b1.x + a1.y * b1.y + a1.z * b1.z + a1.w * b1.w +
              a2.x * b2.x + a2.y * b2.y + a2.z * b2.z + a2.w * b2.w;
#pragma unroll
    for (int off = 32; off; off >>= 1) s += __shfl_down(s, off, 64);
    if (lane == 0) out[r] = lrelu(s + p3b[0]);
}

extern "C" void kernel_launch(void* const* d_in, const int* in_sizes, int n_in,
                              void* d_out, int out_size, void* d_ws, size_t ws_size,
                              hipStream_t stream) {
    const float* out1 = (const float*)d_in[0];
    const float* out2 = (const float*)d_in[1];
    const float* out3 = (const float*)d_in[2];
    const float* theta_w = (const float*)d_in[3];
    const float* phi_w = (const float*)d_in[4];
    const float* g_w = (const float*)d_in[5];
    const float* W_w = (const float*)d_in[6];
    const float* W_b = (const float*)d_in[7];
    const float* p1_w = (const float*)d_in[8];
    const float* p2_w = (const float*)d_in[9];
    const float* p3_w = (const float*)d_in[10];
    const float* p3_b = (const float*)d_in[11];
    float* outp = (float*)d_out;

    // ---- workspace layout (bytes) ----
    char* wsb = (char*)d_ws;
    float* Wg_w = (float*)(wsb + 0);                          // 512^2 fp32
    float* Mw   = (float*)(wsb + 1048576);                    // 512^2 fp32
    unsigned short* Whi = (unsigned short*)(wsb + 2097152);   // 1024x512 bf16 (M | Wg_w)
    unsigned short* Wlo = (unsigned short*)(wsb + 3145728);
    unsigned short* p1h = (unsigned short*)(wsb + 4194304);
    unsigned short* p1l = (unsigned short*)(wsb + 4718592);
    unsigned short* p2h = (unsigned short*)(wsb + 5242880);
    unsigned short* p2l = (unsigned short*)(wsb + 5767168);
    unsigned short* Xh  = (unsigned short*)(wsb + 6291456);   // 6144x512 bf16
    unsigned short* Xl  = (unsigned short*)(wsb + 12582912);
    unsigned short* Yh  = (unsigned short*)(wsb + 18874368);  // 6144x512 bf16
    unsigned short* Yl  = (unsigned short*)(wsb + 25165824);
    float* Wg = (float*)(wsb + 31457280);                     // 6144x512 fp32
    float* D  = (float*)(wsb + 44040192);                     // 144x128x128 fp32
    // aliases (dead-buffer reuse):
    unsigned short* Plh = (unsigned short*)(wsb + 18874368);  // over Yh (dead after gram)
    unsigned short* Pll = (unsigned short*)(wsb + 20971520);
    unsigned short* h1h = (unsigned short*)(wsb + 25165824);  // over Yl (dead after gram)
    unsigned short* h1l = (unsigned short*)(wsb + 27262976);
    float* h2 = (float*)(wsb + 6291456);                      // over Xh (dead after mix)

    // 1. Wg_w = W_w @ g_w ; Mw = theta_w^T @ phi_w
    k_gemm2<<<dim3(8, 8, 2), 256, 0, stream>>>(W_w, g_w, Wg_w, theta_w, phi_w, Mw);
    // 2. split weights to bf16 hi/lo (M | Wg_w stacked; p1; p2)
    k_split_w<<<dim3(256, 4), 256, 0, stream>>>(Mw, Wg_w, p1_w, p2_w,
                                                Whi, Wlo, p1h, p1l, p2h, p2l);
    // 3. transpose+split inputs
    k_splitx<<<dim3(16, 4, 48), dim3(32, 8), 0, stream>>>(out1, out2, out3, Xh, Xl);
    // 4. stage A: Y (bf16 hi/lo) + Wg (fp32)
    k_ga<<<dim3(48, 8), 256, 0, stream>>>(Whi, Wlo, Xh, Xl, Yh, Yl, Wg);
    // 5. gram matrices: D = X . Y^T
    k_gram2<<<dim3(144), 256, 0, stream>>>(Xh, Xl, Yh, Yl, D);
    // 6. softmax + mix + residual + pool
    k_mix<<<dim3(2048), 512, 0, stream>>>(Xh, Xl, Wg, D, W_b, Plh, Pll);
    // 7. MLP
    k_mlp<true><<<dim3(16, 4), 256, 0, stream>>>(Plh, Pll, p1h, p1l, h1h, h1l, nullptr);
    k_mlp<false><<<dim3(16, 4), 256, 0, stream>>>(h1h, h1l, p2h, p2l, nullptr, nullptr, h2);
    // 8. final projection
    k_final<<<dim3(512), 256, 0, stream>>>(h2, p3_w, p3_b, outp);
}

// Round 8
// 155.700 us; speedup vs baseline: 5.1360x; 1.1613x over previous
//
#include <hip/hip_runtime.h>

typedef __attribute__((ext_vector_type(8))) short short8;
typedef __attribute__((ext_vector_type(4))) float float4v;
typedef __attribute__((ext_vector_type(4))) unsigned int uint4v;
typedef __attribute__((ext_vector_type(4))) unsigned short ushort4v;

__device__ __forceinline__ float lrelu(float v) { return v >= 0.f ? v : 0.01f * v; }

__device__ __forceinline__ unsigned short f2bf(float x) {
    union { float f; unsigned u; } c; c.f = x;
    unsigned r = (c.u + 0x7FFFu + ((c.u >> 16) & 1u)) >> 16;
    return (unsigned short)r;
}
__device__ __forceinline__ float bf2f(unsigned short h) {
    union { unsigned u; float f; } c; c.u = ((unsigned)h) << 16;
    return c.f;
}

// async global->LDS, 16B per lane. LDS dest must be wave-uniform base
// (HW adds lane*16); global src is per-lane (pre-swizzled).
__device__ __forceinline__ void gload16(const unsigned short* g, unsigned short* l) {
    __builtin_amdgcn_global_load_lds(
        (const __attribute__((address_space(1))) unsigned int*)g,
        (__attribute__((address_space(3))) unsigned int*)l, 16, 0, 0);
}

// ===========================================================================
// Shared MFMA core: C[128x128] += A[128xK] * B[128xK]^T, K=512, split-bf16
// (hi*hi + hi*lo + lo*hi -> ~fp32 precision). 256 threads, 4 waves 2x2.
// LDS: 4 tiles [128][64] bf16. global_load_lds direct staging: LDS linear,
// global source pre-swizzled with the same XOR involution the reads use.
// ===========================================================================
__device__ __forceinline__ void mfma_core(
    const unsigned short* __restrict__ Ah, const unsigned short* __restrict__ Al, int lda,
    const unsigned short* __restrict__ Bh, const unsigned short* __restrict__ Bl, int ldb,
    unsigned short* lds, float4v acc[4][4]) {
    const int tid = threadIdx.x;
    const int lane = tid & 63, wave = tid >> 6;
    const int wm = wave >> 1, wn = wave & 1;
    const int l15 = lane & 15, lhi = lane >> 4;
    unsigned short* LAh = lds;
    unsigned short* LAl = lds + 8192;
    unsigned short* LBh = lds + 16384;
    unsigned short* LBl = lds + 24576;

    for (int k0 = 0; k0 < 512; k0 += 64) {
#pragma unroll
        for (int tile = 0; tile < 4; ++tile) {
            const unsigned short* s = (tile == 0) ? Ah : (tile == 1) ? Al : (tile == 2) ? Bh : Bl;
            int ld = (tile < 2) ? lda : ldb;
            unsigned short* dbase = lds + tile * 8192;
#pragma unroll
            for (int it = 0; it < 4; ++it) {
                int idx = it * 256 + tid;
                int row = idx >> 3, ch = idx & 7;
                // linear LDS dest (wave-uniform base), swizzled global src
                gload16(&s[row * ld + k0 + ((ch ^ (row & 7)) << 3)],
                        dbase + ((it * 256 + wave * 64) << 3));
            }
        }
        __syncthreads();
#pragma unroll
        for (int ks = 0; ks < 2; ++ks) {
            short8 ah[4], al[4], bh[4], bl[4];
#pragma unroll
            for (int m = 0; m < 4; ++m) {
                int r = wm * 64 + m * 16 + l15;
                int off = r * 64 + (((ks * 4 + lhi) ^ (r & 7)) * 8);
                ah[m] = *(const short8*)&LAh[off];
                al[m] = *(const short8*)&LAl[off];
            }
#pragma unroll
            for (int n = 0; n < 4; ++n) {
                int r = wn * 64 + n * 16 + l15;
                int off = r * 64 + (((ks * 4 + lhi) ^ (r & 7)) * 8);
                bh[n] = *(const short8*)&LBh[off];
                bl[n] = *(const short8*)&LBl[off];
            }
#pragma unroll
            for (int m = 0; m < 4; ++m)
#pragma unroll
                for (int n = 0; n < 4; ++n) {
                    acc[m][n] = __builtin_amdgcn_mfma_f32_16x16x32_bf16(ah[m], bh[n], acc[m][n], 0, 0, 0);
                    acc[m][n] = __builtin_amdgcn_mfma_f32_16x16x32_bf16(ah[m], bl[n], acc[m][n], 0, 0, 0);
                    acc[m][n] = __builtin_amdgcn_mfma_f32_16x16x32_bf16(al[m], bh[n], acc[m][n], 0, 0, 0);
                }
        }
        __syncthreads();
    }
}

// ---------------------------------------------------------------------------
// Straight split to bf16 hi/lo: z=0 W_w, z=1 p1_w, z=2 p2_w. grid (256,3).
// ---------------------------------------------------------------------------
__global__ __launch_bounds__(256) void k_split_w(
    const float* __restrict__ ww, const float* __restrict__ p1w,
    const float* __restrict__ p2w, unsigned short* __restrict__ WwH,
    unsigned short* __restrict__ WwL, unsigned short* __restrict__ p1h,
    unsigned short* __restrict__ p1l, unsigned short* __restrict__ p2h,
    unsigned short* __restrict__ p2l) {
    int z = blockIdx.y;
    const float* src = (z == 0) ? ww : (z == 1) ? p1w : p2w;
    unsigned short* dh = (z == 0) ? WwH : (z == 1) ? p1h : p2h;
    unsigned short* dl = (z == 0) ? WwL : (z == 1) ? p1l : p2l;
    int i4 = blockIdx.x * 256 + threadIdx.x;
    float4v v = ((const float4v*)src)[i4];
    ushort4v h, l;
#pragma unroll
    for (int j = 0; j < 4; ++j) {
        h[j] = f2bf(v[j]);
        l[j] = f2bf(v[j] - bf2f(h[j]));
    }
    ((ushort4v*)dh)[i4] = h;
    ((ushort4v*)dl)[i4] = l;
}

// ---------------------------------------------------------------------------
// Transpose+split 512x512 weights: Dst[i][k] = src[k][i] as bf16 hi/lo.
// z=0 theta->Tt, z=1 phi->Pt, z=2 g_w->Gt. grid (16,16,3), block (32,8).
// ---------------------------------------------------------------------------
__global__ __launch_bounds__(256) void k_split_wT(
    const float* __restrict__ tw, const float* __restrict__ fw,
    const float* __restrict__ gw, unsigned short* __restrict__ TtH,
    unsigned short* __restrict__ TtL, unsigned short* __restrict__ PtH,
    unsigned short* __restrict__ PtL, unsigned short* __restrict__ GtH,
    unsigned short* __restrict__ GtL) {
    int z = blockIdx.z;
    const float* src = (z == 0) ? tw : (z == 1) ? fw : gw;
    unsigned short* dh = (z == 0) ? TtH : (z == 1) ? PtH : GtH;
    unsigned short* dl = (z == 0) ? TtL : (z == 1) ? PtL : GtL;
    int i0 = blockIdx.x * 32, k0 = blockIdx.y * 32;
    __shared__ float tile[32][33];
    int tx = threadIdx.x, ty = threadIdx.y;
#pragma unroll
    for (int i = 0; i < 4; ++i)
        tile[ty + i * 8][tx] = src[(k0 + ty + i * 8) * 512 + i0 + tx];
    __syncthreads();
#pragma unroll
    for (int i = 0; i < 4; ++i) {
        int row = i0 + ty + i * 8;
        float v = tile[tx][ty + i * 8];  // = src[k0+tx][row]
        unsigned short h = f2bf(v), l = f2bf(v - bf2f(h));
        int idx = row * 512 + k0 + tx;
        dh[idx] = h;
        dl[idx] = l;
    }
}

// ---------------------------------------------------------------------------
// Weight GEMMs via MFMA, epilogue splits into stacked Whi/Wlo [1024][512]:
//   z=1: Mw   = Tt . Pt^T -> rows 0-511    (Mw[i][j] = sum_k theta[k][i] phi[k][j])
//   z=0: Wg_w = Ww . Gt^T -> rows 512-1023 (Wg_w[i][j] = sum_k W_w[i][k] g_w[k][j])
// grid (4,4,2), block 256.
// ---------------------------------------------------------------------------
__global__ __launch_bounds__(256) void k_wgemm(
    const unsigned short* __restrict__ WwH, const unsigned short* __restrict__ WwL,
    const unsigned short* __restrict__ GtH, const unsigned short* __restrict__ GtL,
    const unsigned short* __restrict__ TtH, const unsigned short* __restrict__ TtL,
    const unsigned short* __restrict__ PtH, const unsigned short* __restrict__ PtL,
    unsigned short* __restrict__ Whi, unsigned short* __restrict__ Wlo) {
    __shared__ unsigned short lds[32768];
    int i0 = blockIdx.y * 128, j0 = blockIdx.x * 128;
    bool wg = blockIdx.z == 0;
    const unsigned short* Ah = (wg ? WwH : TtH) + i0 * 512;
    const unsigned short* Al = (wg ? WwL : TtL) + i0 * 512;
    const unsigned short* Bh = (wg ? GtH : PtH) + j0 * 512;
    const unsigned short* Bl = (wg ? GtL : PtL) + j0 * 512;
    float4v acc[4][4];
#pragma unroll
    for (int m = 0; m < 4; ++m)
#pragma unroll
        for (int n = 0; n < 4; ++n) acc[m][n] = (float4v){0.f, 0.f, 0.f, 0.f};

    mfma_core(Ah, Al, 512, Bh, Bl, 512, lds, acc);

    int lane = threadIdx.x & 63, wave = threadIdx.x >> 6;
    int wm = wave >> 1, wn = wave & 1, l15 = lane & 15, lhi = lane >> 4;
    int rowbase = wg ? 512 + i0 : i0;
#pragma unroll
    for (int m = 0; m < 4; ++m)
#pragma unroll
        for (int n = 0; n < 4; ++n) {
            int bcol = j0 + wn * 64 + n * 16 + l15;
#pragma unroll
            for (int i = 0; i < 4; ++i) {
                int r = rowbase + wm * 64 + m * 16 + lhi * 4 + i;
                float v = acc[m][n][i];
                unsigned short h = f2bf(v), l = f2bf(v - bf2f(h));
                Whi[r * 512 + bcol] = h;
                Wlo[r * 512 + bcol] = l;
            }
        }
}

// ---------------------------------------------------------------------------
// Transpose+split inputs: Xt[((b*128+t)*3+k)*512 + c] = in_k[b][c][t] (hi/lo)
// ---------------------------------------------------------------------------
__global__ __launch_bounds__(256) void k_splitx(const float* __restrict__ o1,
                                                const float* __restrict__ o2,
                                                const float* __restrict__ o3,
                                                unsigned short* __restrict__ Xh,
                                                unsigned short* __restrict__ Xl) {
    int z = blockIdx.z;
    int b = z / 3, k = z - b * 3;
    const float* In = (k == 0) ? o1 : ((k == 1) ? o2 : o3);
    int c0 = blockIdx.x * 32, t0 = blockIdx.y * 32;
    __shared__ float tile[32][33];
    int tx = threadIdx.x, ty = threadIdx.y;
#pragma unroll
    for (int i = 0; i < 4; ++i)
        tile[ty + i * 8][tx] = In[(b * 512 + c0 + ty + i * 8) * 128 + t0 + tx];
    __syncthreads();
#pragma unroll
    for (int i = 0; i < 4; ++i) {
        int t = t0 + ty + i * 8;
        float v = tile[tx][ty + i * 8];
        unsigned short h = f2bf(v), l = f2bf(v - bf2f(h));
        int idx = ((b * 128 + t) * 3 + k) * 512 + c0 + tx;
        Xh[idx] = h;
        Xl[idx] = l;
    }
}

// ---------------------------------------------------------------------------
// Stage A via MFMA: grid (48, 8): x = b*3+kin, y = o-tile
//   y 0-3 -> Y = Mw . x (bf16 hi/lo), y 4-7 -> Wg = Wg_w . x (fp32)
// ---------------------------------------------------------------------------
__global__ __launch_bounds__(256) void k_ga(
    const unsigned short* __restrict__ Whi, const unsigned short* __restrict__ Wlo,
    const unsigned short* __restrict__ Xh, const unsigned short* __restrict__ Xl,
    unsigned short* __restrict__ Yh, unsigned short* __restrict__ Yl,
    float* __restrict__ Wg) {
    __shared__ unsigned short lds[32768];
    int bk = blockIdx.x, y = blockIdx.y;
    int b = bk / 3, kin = bk - b * 3;
    int bbase = (b * 384 + kin) * 512;
    float4v acc[4][4];
#pragma unroll
    for (int m = 0; m < 4; ++m)
#pragma unroll
        for (int n = 0; n < 4; ++n) acc[m][n] = (float4v){0.f, 0.f, 0.f, 0.f};

    mfma_core(Whi + y * 128 * 512, Wlo + y * 128 * 512, 512,
              Xh + bbase, Xl + bbase, 1536, lds, acc);

    int lane = threadIdx.x & 63, wave = threadIdx.x >> 6;
    int wm = wave >> 1, wn = wave & 1, l15 = lane & 15, lhi = lane >> 4;
    int wsel = y >> 2, o0 = (y & 3) * 128;
#pragma unroll
    for (int m = 0; m < 4; ++m)
#pragma unroll
        for (int n = 0; n < 4; ++n) {
            int o_in = wm * 64 + m * 16 + lhi * 4;
            int t = wn * 64 + n * 16 + l15;
            int idx = bbase + t * 1536 + o0 + o_in;
            if (wsel == 1) {
                *(float4v*)&Wg[idx] = acc[m][n];
            } else {
                ushort4v h, l;
#pragma unroll
                for (int i = 0; i < 4; ++i) {
                    float v = acc[m][n][i];
                    h[i] = f2bf(v);
                    l[i] = f2bf(v - bf2f(h[i]));
                }
                *(ushort4v*)&Yh[idx] = h;
                *(ushort4v*)&Yl[idx] = l;
            }
        }
}

// ---------------------------------------------------------------------------
// Gram via MFMA: D[mat][t1][t2] = X[b,t1,k,:] . Y[b,t2,kp,:]
// grid 144, XCD-swizzled so same-b mats share an XCD's L2.
// ---------------------------------------------------------------------------
__global__ __launch_bounds__(256) void k_gram2(
    const unsigned short* __restrict__ Xh, const unsigned short* __restrict__ Xl,
    const unsigned short* __restrict__ Yh, const unsigned short* __restrict__ Yl,
    float* __restrict__ D) {
    __shared__ unsigned short lds[32768];
    int orig = blockIdx.x;
    int mat = (orig & 7) * 18 + (orig >> 3);  // 144 = 8 * 18, bijective
    int b = mat / 9, r9 = mat - b * 9, k = r9 / 3, kp = r9 - k * 3;
    int Ab = (b * 384 + k) * 512, Bb = (b * 384 + kp) * 512;
    float4v acc[4][4];
#pragma unroll
    for (int m = 0; m < 4; ++m)
#pragma unroll
        for (int n = 0; n < 4; ++n) acc[m][n] = (float4v){0.f, 0.f, 0.f, 0.f};

    mfma_core(Xh + Ab, Xl + Ab, 1536, Yh + Bb, Yl + Bb, 1536, lds, acc);

    int lane = threadIdx.x & 63, wave = threadIdx.x >> 6;
    int wm = wave >> 1, wn = wave & 1, l15 = lane & 15, lhi = lane >> 4;
    float* Dm = D + mat * 16384;
#pragma unroll
    for (int m = 0; m < 4; ++m)
#pragma unroll
        for (int n = 0; n < 4; ++n) {
            int t2 = wn * 64 + n * 16 + l15;
#pragma unroll
            for (int i = 0; i < 4; ++i) {
                int t1 = wm * 64 + m * 16 + lhi * 4 + i;
                Dm[t1 * 128 + t2] = acc[m][n][i];
            }
        }
}

// ---------------------------------------------------------------------------
// MLP layer via MFMA: C[r][o] = lrelu( A[r,:] . W[o,:] )
// ---------------------------------------------------------------------------
template <bool SPLIT_OUT>
__global__ __launch_bounds__(256) void k_mlp(
    const unsigned short* __restrict__ Ahi, const unsigned short* __restrict__ Alo,
    const unsigned short* __restrict__ Bhi, const unsigned short* __restrict__ Blo,
    unsigned short* __restrict__ Ch, unsigned short* __restrict__ Cl,
    float* __restrict__ Cf) {
    __shared__ unsigned short lds[32768];
    int r0 = blockIdx.x * 128, o0 = blockIdx.y * 128;
    float4v acc[4][4];
#pragma unroll
    for (int m = 0; m < 4; ++m)
#pragma unroll
        for (int n = 0; n < 4; ++n) acc[m][n] = (float4v){0.f, 0.f, 0.f, 0.f};

    mfma_core(Ahi + r0 * 512, Alo + r0 * 512, 512, Bhi + o0 * 512, Blo + o0 * 512, 512, lds, acc);

    int lane = threadIdx.x & 63, wave = threadIdx.x >> 6;
    int wm = wave >> 1, wn = wave & 1, l15 = lane & 15, lhi = lane >> 4;
#pragma unroll
    for (int m = 0; m < 4; ++m)
#pragma unroll
        for (int n = 0; n < 4; ++n) {
            int o = o0 + wn * 64 + n * 16 + l15;
#pragma unroll
            for (int i = 0; i < 4; ++i) {
                int r = r0 + wm * 64 + m * 16 + lhi * 4 + i;
                float v = lrelu(acc[m][n][i]);
                if (SPLIT_OUT) {
                    unsigned short h = f2bf(v), l = f2bf(v - bf2f(h));
                    Ch[r * 512 + o] = h;
                    Cl[r * 512 + o] = l;
                } else {
                    Cf[r * 512 + o] = v;
                }
            }
        }
}

// ---------------------------------------------------------------------------
// Mix (round-4 proven body + XCD swizzle): per (b,t): gather f from D,
// softmax rows, one o per thread with wg[24]/xw[24] preloads.
// grid 2048 (XCD r gets bids [r*256,(r+1)*256) = exactly 2 b's), block 512.
// ---------------------------------------------------------------------------
__global__ __launch_bounds__(512) void k_mix(
    const unsigned short* __restrict__ Xh, const unsigned short* __restrict__ Xl,
    const float* __restrict__ Wg, const float* __restrict__ D,
    const float* __restrict__ W_b, unsigned short* __restrict__ Plh,
    unsigned short* __restrict__ Pll) {
    int orig = blockIdx.x;
    int bid = ((orig & 7) << 8) | (orig >> 3);  // 2048 = 8 * 256, bijective
    int b = bid >> 7, t = bid & 127;
    int tid = threadIdx.x;

    __shared__ float Pm[24][28];

    for (int idx = tid; idx < 576; idx += 512) {
        int n = idx / 24, m = idx - n * 24;
        int j = n / 3, k = n - j * 3;
        int jp = m / 3, kp = m - jp * 3;
        int t1 = t - 7 + j, t2 = t - 7 + jp;
        float v = 0.f;
        if (t1 >= 0 && t2 >= 0)
            v = D[((((b * 3 + k) * 3 + kp) * 128 + t1) << 7) + t2];
        Pm[n][m] = v;
    }
    __syncthreads();

    if (tid < 24) {
        float mx = -1e30f;
#pragma unroll
        for (int m = 0; m < 24; ++m) mx = fmaxf(mx, Pm[tid][m]);
        float e[24], sum = 0.f;
#pragma unroll
        for (int m = 0; m < 24; ++m) { e[m] = __expf(Pm[tid][m] - mx); sum += e[m]; }
        float inv = 1.0f / sum;
#pragma unroll
        for (int m = 0; m < 24; ++m) Pm[tid][m] = e[m] * inv;
    }
    __syncthreads();

    int o = tid;
    float wg[24], xw[24];
#pragma unroll
    for (int m = 0; m < 24; ++m) {
        int j = m / 3, k = m - j * 3;
        int tp = t - 7 + j;
        int base = (((b * 128 + tp) * 3 + k) << 9) + o;
        wg[m] = (tp >= 0) ? Wg[base] : 0.f;
        xw[m] = (tp >= 0) ? (bf2f(Xh[base]) + bf2f(Xl[base])) : 0.f;
    }
    float wb = W_b[o];
    float pooled = -1e30f;
#pragma unroll
    for (int n = 0; n < 24; ++n) {
        float s = 0.f;
#pragma unroll
        for (int m = 0; m < 24; ++m) s += Pm[n][m] * wg[m];
        s += wb + xw[n];
        pooled = fmaxf(pooled, s);
    }
    int oidx = ((t * 16 + b) << 9) + o;
    unsigned short h = f2bf(pooled), l = f2bf(pooled - bf2f(h));
    Plh[oidx] = h;
    Pll[oidx] = l;
}

// ---------------------------------------------------------------------------
// out[r] = lrelu( sum_c H[r][c]*p3w[c] + p3b )   one wave per row
// ---------------------------------------------------------------------------
__global__ __launch_bounds__(256) void k_final(const float* __restrict__ H,
                                               const float* __restrict__ p3w,
                                               const float* __restrict__ p3b,
                                               float* __restrict__ out) {
    int r = blockIdx.x * 4 + (threadIdx.x >> 6);
    int lane = threadIdx.x & 63;
    const float4* h4 = (const float4*)&H[r << 9];
    const float4* w4 = (const float4*)p3w;
    float4 a1 = h4[lane], a2 = h4[lane + 64];
    float4 b1 = w4[lane], b2 = w4[lane + 64];
    float s = a1.x * b1.x + a1.y * b1.y + a1.z * b1.z + a1.w * b1.w +
              a2.x * b2.x + a2.y * b2.y + a2.z * b2.z + a2.w * b2.w;
#pragma unroll
    for (int off = 32; off; off >>= 1) s += __shfl_down(s, off, 64);
    if (lane == 0) out[r] = lrelu(s + p3b[0]);
}

extern "C" void kernel_launch(void* const* d_in, const int* in_sizes, int n_in,
                              void* d_out, int out_size, void* d_ws, size_t ws_size,
                              hipStream_t stream) {
    const float* out1 = (const float*)d_in[0];
    const float* out2 = (const float*)d_in[1];
    const float* out3 = (const float*)d_in[2];
    const float* theta_w = (const float*)d_in[3];
    const float* phi_w = (const float*)d_in[4];
    const float* g_w = (const float*)d_in[5];
    const float* W_w = (const float*)d_in[6];
    const float* W_b = (const float*)d_in[7];
    const float* p1_w = (const float*)d_in[8];
    const float* p2_w = (const float*)d_in[9];
    const float* p3_w = (const float*)d_in[10];
    const float* p3_b = (const float*)d_in[11];
    float* outp = (float*)d_out;

    // ---- workspace layout (bytes) ----
    char* wsb = (char*)d_ws;
    unsigned short* Whi = (unsigned short*)(wsb + 0);         // 1024x512 bf16 (Mw | Wg_w)
    unsigned short* Wlo = (unsigned short*)(wsb + 1048576);
    unsigned short* p1h = (unsigned short*)(wsb + 2097152);
    unsigned short* p1l = (unsigned short*)(wsb + 2621440);
    unsigned short* p2h = (unsigned short*)(wsb + 3145728);
    unsigned short* p2l = (unsigned short*)(wsb + 3670016);
    unsigned short* WwH = (unsigned short*)(wsb + 4194304);
    unsigned short* WwL = (unsigned short*)(wsb + 4718592);
    unsigned short* TtH = (unsigned short*)(wsb + 5242880);
    unsigned short* TtL = (unsigned short*)(wsb + 5767168);
    unsigned short* PtH = (unsigned short*)(wsb + 6291456);
    unsigned short* PtL = (unsigned short*)(wsb + 6815744);
    unsigned short* GtH = (unsigned short*)(wsb + 7340032);
    unsigned short* GtL = (unsigned short*)(wsb + 7864320);
    unsigned short* Xh  = (unsigned short*)(wsb + 8388608);   // 6144x512 bf16
    unsigned short* Xl  = (unsigned short*)(wsb + 14680064);
    unsigned short* Yh  = (unsigned short*)(wsb + 20971520);  // 6144x512 bf16
    unsigned short* Yl  = (unsigned short*)(wsb + 27262976);
    float* Wg = (float*)(wsb + 33554432);                     // 6144x512 fp32
    float* D  = (float*)(wsb + 46137344);                     // 144x128x128 fp32
    // aliases (dead-buffer reuse):
    unsigned short* Plh = (unsigned short*)(wsb + 20971520);  // over Yh (dead after gram)
    unsigned short* Pll = (unsigned short*)(wsb + 23068672);
    unsigned short* h1h = (unsigned short*)(wsb + 27262976);  // over Yl (dead after gram)
    unsigned short* h1l = (unsigned short*)(wsb + 29360128);
    float* h2 = (float*)(wsb + 8388608);                      // over Xh (dead after mix)

    // 1. split raw weights: straight (W_w, p1, p2) + transposed (theta, phi, g)
    k_split_w<<<dim3(256, 3), 256, 0, stream>>>(W_w, p1_w, p2_w,
                                                WwH, WwL, p1h, p1l, p2h, p2l);
    k_split_wT<<<dim3(16, 16, 3), dim3(32, 8), 0, stream>>>(theta_w, phi_w, g_w,
                                                            TtH, TtL, PtH, PtL, GtH, GtL);
    // 2. transpose+split inputs (independent of weight GEMMs)
    k_splitx<<<dim3(16, 4, 48), dim3(32, 8), 0, stream>>>(out1, out2, out3, Xh, Xl);
    // 3. weight GEMMs via MFMA: Mw = Tt.Pt^T ; Wg_w = Ww.Gt^T -> Whi/Wlo stacked
    k_wgemm<<<dim3(4, 4, 2), 256, 0, stream>>>(WwH, WwL, GtH, GtL, TtH, TtL,
                                               PtH, PtL, Whi, Wlo);
    // 4. stage A: Y (bf16 hi/lo) + Wg (fp32)
    k_ga<<<dim3(48, 8), 256, 0, stream>>>(Whi, Wlo, Xh, Xl, Yh, Yl, Wg);
    // 5. gram matrices: D = X . Y^T
    k_gram2<<<dim3(144), 256, 0, stream>>>(Xh, Xl, Yh, Yl, D);
    // 6. softmax + mix + residual + pool
    k_mix<<<dim3(2048), 512, 0, stream>>>(Xh, Xl, Wg, D, W_b, Plh, Pll);
    // 7. MLP
    k_mlp<true><<<dim3(16, 4), 256, 0, stream>>>(Plh, Pll, p1h, p1l, h1h, h1l, nullptr);
    k_mlp<false><<<dim3(16, 4), 256, 0, stream>>>(h1h, h1l, p2h, p2l, nullptr, nullptr, h2);
    // 8. final projection
    k_final<<<dim3(512), 256, 0, stream>>>(h2, p3_w, p3_b, outp);
}